// Round 8
// baseline (284.354 us; speedup 1.0000x reference)
//
#include <hip/hip_runtime.h>
#include <hip/hip_bf16.h>

#define BIGF 1e30f
#define TC 80   // channels
#define TN 512  // sequence length (N == M)
#define L2E 1.4426950408889634f   // log2(e)
#define LN2 0.6931471805599453f   // 1/log2(e)

typedef float f32x4 __attribute__((ext_vector_type(4)));
typedef __attribute__((address_space(1))) const unsigned int gu32;
typedef __attribute__((address_space(3))) unsigned int lu32;

// ---------------------------------------------------------------------------
// Kernel 1: pairwise squared distances, SKEWED ILP-4 layout, log2e-scaled.
//
// Logical: D'[jj][i] = ||x_i - y_jj||^2 (args swapped at launch; bitwise D^T).
// Storage: F[p][i],  p = (jj + (i>>1)) & 511  (pipeline v = i>>1 owns 2 rows).
// Bijection per batch (for fixed i, jj->p is a bijection). At sweep iteration
// s, ALL active pipelines' data sits in row p = s & 511: the mod-512 wrap is
// exactly consistent with the active window, so the sweep reads one uniform
// contiguous 2 KB row per iteration with NO clamping, head/tail included.
// Epilogue: each float4 spans two pipelines -> two float2 stores (rows p, p+1).
// ---------------------------------------------------------------------------
__global__ __launch_bounds__(256) void pairdist_kernel(
    const float* __restrict__ x, const float* __restrict__ y,
    float* __restrict__ F) {
  const int b  = blockIdx.z;
  const int n0 = blockIdx.x * 64;   // jj tile (rows of D')
  const int m0 = blockIdx.y * 64;   // i tile (cols of D')

  __shared__ float xs[TC][64];
  __shared__ float ys[TC][64];
  __shared__ float xxs[64];
  __shared__ float yys[64];

  const float* xb = x + (size_t)b * TC * TN;
  const float* yb = y + (size_t)b * TC * TN;
  const int tid = threadIdx.x;

  for (int idx = tid; idx < TC * 64; idx += 256) {
    int c = idx >> 6, n = idx & 63;
    xs[c][n] = xb[c * TN + n0 + n];
    ys[c][n] = yb[c * TN + m0 + n];
  }
  __syncthreads();

  if (tid < 64) {
    float s = 0.f;
    for (int c = 0; c < TC; ++c) { float v = xs[c][tid]; s += v * v; }
    xxs[tid] = s;
  } else if (tid < 128) {
    int t2 = tid - 64;
    float s = 0.f;
    for (int c = 0; c < TC; ++c) { float v = ys[c][t2]; s += v * v; }
    yys[t2] = s;
  }
  __syncthreads();

  const int tm = tid & 15, tn = tid >> 4;
  float acc[4][4] = {};
  for (int c = 0; c < TC; ++c) {
    float4 xa = *(const float4*)&xs[c][tn * 4];
    float4 ya = *(const float4*)&ys[c][tm * 4];
    float xv[4] = {xa.x, xa.y, xa.z, xa.w};
    float yv[4] = {ya.x, ya.y, ya.z, ya.w};
#pragma unroll
    for (int a = 0; a < 4; ++a)
#pragma unroll
      for (int q = 0; q < 4; ++q) acc[a][q] += xv[a] * yv[q];
  }

  float* Fb = F + (size_t)b * TN * TN;
  const int i0 = m0 + tm * 4;         // first of 4 consecutive D' columns
  const int v0 = i0 >> 1;             // pipeline of columns i0, i0+1
#pragma unroll
  for (int a = 0; a < 4; ++a) {
    int jj = n0 + tn * 4 + a;         // row of D'
    float xxv = xxs[tn * 4 + a];
    float4 o;
    o.x = (xxv + yys[tm * 4 + 0] - 2.f * acc[a][0]) * L2E;
    o.y = (xxv + yys[tm * 4 + 1] - 2.f * acc[a][1]) * L2E;
    o.z = (xxv + yys[tm * 4 + 2] - 2.f * acc[a][2]) * L2E;
    o.w = (xxv + yys[tm * 4 + 3] - 2.f * acc[a][3]) * L2E;
    int p0 = (jj + v0) & (TN - 1);
    int p1 = (jj + v0 + 1) & (TN - 1);
    *(float2*)&Fb[(size_t)p0 * TN + i0]     = make_float2(o.x, o.y);
    *(float2*)&Fb[(size_t)p1 * TN + i0 + 2] = make_float2(o.z, o.w);
  }
}

// ---------------------------------------------------------------------------
// Kernel 2: soft-DTW, ILP-4 slab sweep (256 pipelines x 2 rows), LDS ring.
//
// Round-7 post-mortem: per-iter 616 cy = ~250 issue + ~360 EXPOSED chain
// latency; 2 chains couldn't cover a ~35 cy/cell latency bubble. Now lane t
// runs FOUR chains (pipelines 4t+k, k=0..3; chain k owns DP rows 8t+2k+1,
// 8t+2k+2): per-iter path = 2 cells, 4-way interleave hides it under issue.
// 767 iterations (s = 0..766); pipeline v computes col j = s - v + 1.
//
// Uniform row read: iteration s consumes exactly F[s & 511][0..511] — one
// contiguous 2 KB row, identical address for all head/tail phases (see
// kernel-1 comment). Lane t takes floats 8t..8t+7 (chains 0..3, 2 each).
// Pre-start pipelines read finite junk; all-BIG inputs give
// dv + 1e30 - log2(3) -> 1e30 exact, so boundaries self-sustain bitwise.
// Post-finish junk is never consumed (pipeline 255 retires at s=766).
//
// Handoffs: chain k's up row = chain k-1's bottom, 1-iteration delay
// (lane-local renames for k=1..3; DPP wave_shr:1 old=BIG from lane t-1's
// chain 3 for k=0). Verified LDS-ring machinery from rounds 4-7: 8 slots,
// 16 outstanding DMA, vmcnt(0) per 8-body block (staged ~1 block earlier),
// atomic 16x ds_read_b128 + lgkmcnt(0). 767 = 95 x 8 + 7 tail.
// ---------------------------------------------------------------------------
__global__ __launch_bounds__(64) __attribute__((amdgpu_waves_per_eu(1)))
void sdtw_kernel(const float* __restrict__ Ft, float* __restrict__ out) {
  const int b = blockIdx.x;
  const int t = threadIdx.x;
  const float* Fb = Ft + (size_t)b * TN * TN;

  __shared__ float ring[8][512];      // 8 slots x 2 KB

  // Chain state: pK[0..1] = left values of chain K's two rows.
  float p0[2], p1[2], p2[2], p3[2];
  p0[0] = p0[1] = p1[0] = p1[1] = BIGF;
  p2[0] = p2[1] = p3[0] = p3[1] = BIGF;
  float u0c = BIGF, u0p = (t == 0) ? 0.f : BIGF;  // R[8t][j], R[8t][j-1]
  float u1c = BIGF, u1p = BIGF;
  float u2c = BIGF, u2p = BIGF;
  float u3c = BIGF, u3p = BIGF;

  // Stage slot <- iteration u: uniform row p = u & 511, lane t takes 32 B.
  auto stage = [&](int slot, int u) {
    const float* g = Fb + (size_t)(u & (TN - 1)) * TN + t * 8;
    __builtin_amdgcn_global_load_lds((gu32*)g,       (lu32*)&ring[slot][0],   16, 0, 0);
    __builtin_amdgcn_global_load_lds((gu32*)(g + 4), (lu32*)&ring[slot][256], 16, 0, 0);
  };

  const unsigned lbase =
      (unsigned)(size_t)(__attribute__((address_space(3))) float*)&ring[0][0];

  // One DP cell: softmin3 in log2 domain, 3 trans (exact min3/med3/max3 sort;
  // the min's exp2 term is exactly 1). Bit-identical to round 7 (absmax 0.0).
  auto cell = [&](float d, float r0, float r1, float r2) -> float {
    float mn, md, mx;
    asm("v_min3_f32 %0, %3, %4, %5\n\t"
        "v_med3_f32 %1, %3, %4, %5\n\t"
        "v_max3_f32 %2, %3, %4, %5"
        : "=&v"(mn), "=&v"(md), "=&v"(mx)
        : "v"(r0), "v"(r1), "v"(r2));
    float e1 = __builtin_amdgcn_exp2f(mn - md);
    float e2 = __builtin_amdgcn_exp2f(mn - mx);
    float dm = d + mn;
    float ss = (1.0f + e1) + e2;
    return dm - __builtin_amdgcn_logf(ss);
  };

  // da = floats 8t..8t+3 (chains 0,1), db = floats 8t+4..8t+7 (chains 2,3).
  auto body = [&](f32x4 da, f32x4 db) {
    // Cell 0 (top row) of each chain — 4 independent ops feed the scheduler.
    float c00 = cell(da[0], u0p, u0c, p0[0]);
    float c10 = cell(da[2], u1p, u1c, p1[0]);
    float c20 = cell(db[0], u2p, u2c, p2[0]);
    float c30 = cell(db[2], u3p, u3c, p3[0]);
    // Cell 1 (bottom row): diag = old p[0], up = cell 0, left = old p[1].
    float c01 = cell(da[1], p0[0], c00, p0[1]);
    float c11 = cell(da[3], p1[0], c10, p1[1]);
    float c21 = cell(db[1], p2[0], c20, p2[1]);
    float c31 = cell(db[3], p3[0], c30, p3[1]);
    p0[0] = c00; p0[1] = c01;
    p1[0] = c10; p1[1] = c11;
    p2[0] = c20; p2[1] = c21;
    p3[0] = c30; p3[1] = c31;
    // Handoffs (consumed next iteration; 1-column stagger per pipeline).
    u1p = u1c; u1c = c01;
    u2p = u2c; u2c = c11;
    u3p = u3c; u3c = c21;
    u0p = u0c;
    int sh = __builtin_amdgcn_update_dpp(
        __float_as_int(BIGF), __float_as_int(c31), 0x138, 0xf, 0xf, false);
    u0c = __int_as_float(sh);   // lane t-1's chain-3 bottom; lane 0 gets BIG
  };

  // Preamble: stage slots 0..7 (iters 0..7) -> 16 outstanding DMA.
  stage(0, 0); stage(1, 1); stage(2, 2); stage(3, 3);
  stage(4, 4); stage(5, 5); stage(6, 6); stage(7, 7);

  f32x4 a0, b0, a1, b1, a2, b2, a3, b3, a4, b4, a5, b5, a6, b6, a7, b7;

  // Main: 95 blocks x 8 bodies (iters 0..759).
  int s = 0;
  for (int blk = 0; blk < 95; ++blk, s += 8) {
    // DMAs for these 8 slots were staged one full block (~2500 cy) ago.
    asm volatile("s_waitcnt vmcnt(0)" ::: "memory");
    unsigned ad = lbase + (unsigned)(t * 16);
    asm volatile(
        "ds_read_b128 %0, %16\n\t"
        "ds_read_b128 %1, %16 offset:1024\n\t"
        "ds_read_b128 %2, %16 offset:2048\n\t"
        "ds_read_b128 %3, %16 offset:3072\n\t"
        "ds_read_b128 %4, %16 offset:4096\n\t"
        "ds_read_b128 %5, %16 offset:5120\n\t"
        "ds_read_b128 %6, %16 offset:6144\n\t"
        "ds_read_b128 %7, %16 offset:7168\n\t"
        "ds_read_b128 %8, %16 offset:8192\n\t"
        "ds_read_b128 %9, %16 offset:9216\n\t"
        "ds_read_b128 %10, %16 offset:10240\n\t"
        "ds_read_b128 %11, %16 offset:11264\n\t"
        "ds_read_b128 %12, %16 offset:12288\n\t"
        "ds_read_b128 %13, %16 offset:13312\n\t"
        "ds_read_b128 %14, %16 offset:14336\n\t"
        "ds_read_b128 %15, %16 offset:15360\n\t"
        "s_waitcnt lgkmcnt(0)"
        : "=&v"(a0), "=&v"(b0), "=&v"(a1), "=&v"(b1),
          "=&v"(a2), "=&v"(b2), "=&v"(a3), "=&v"(b3),
          "=&v"(a4), "=&v"(b4), "=&v"(a5), "=&v"(b5),
          "=&v"(a6), "=&v"(b6), "=&v"(a7), "=&v"(b7)
        : "v"(ad)
        : "memory");
    // Refill all 8 slots for the NEXT block (reads above already complete).
    stage(0, s + 8);  stage(1, s + 9);
    stage(2, s + 10); stage(3, s + 11);
    stage(4, s + 12); stage(5, s + 13);
    stage(6, s + 14); stage(7, s + 15);

    body(a0, b0); body(a1, b1); body(a2, b2); body(a3, b3);
    body(a4, b4); body(a5, b5); body(a6, b6); body(a7, b7);
  }

  // Tail: iters 760..766 (7 bodies, slots 0..6; no refills).
  asm volatile("s_waitcnt vmcnt(0)" ::: "memory");
  {
    unsigned ad = lbase + (unsigned)(t * 16);
    asm volatile(
        "ds_read_b128 %0, %14\n\t"
        "ds_read_b128 %1, %14 offset:1024\n\t"
        "ds_read_b128 %2, %14 offset:2048\n\t"
        "ds_read_b128 %3, %14 offset:3072\n\t"
        "ds_read_b128 %4, %14 offset:4096\n\t"
        "ds_read_b128 %5, %14 offset:5120\n\t"
        "ds_read_b128 %6, %14 offset:6144\n\t"
        "ds_read_b128 %7, %14 offset:7168\n\t"
        "ds_read_b128 %8, %14 offset:8192\n\t"
        "ds_read_b128 %9, %14 offset:9216\n\t"
        "ds_read_b128 %10, %14 offset:10240\n\t"
        "ds_read_b128 %11, %14 offset:11264\n\t"
        "ds_read_b128 %12, %14 offset:12288\n\t"
        "ds_read_b128 %13, %14 offset:13312\n\t"
        "s_waitcnt lgkmcnt(0)"
        : "=&v"(a0), "=&v"(b0), "=&v"(a1), "=&v"(b1),
          "=&v"(a2), "=&v"(b2), "=&v"(a3), "=&v"(b3),
          "=&v"(a4), "=&v"(b4), "=&v"(a5), "=&v"(b5),
          "=&v"(a6), "=&v"(b6)
        : "v"(ad)
        : "memory");
  }
  body(a0, b0); body(a1, b1); body(a2, b2); body(a3, b3);
  body(a4, b4); body(a5, b5); body(a6, b6);               // 760..766

  // R[512][512] = pipeline 255 (lane 63, chain 3) bottom row at s=766.
  if (t == 63) out[b] = p3[1] * LN2;
}

extern "C" void kernel_launch(void* const* d_in, const int* in_sizes, int n_in,
                              void* d_out, int out_size, void* d_ws, size_t ws_size,
                              hipStream_t stream) {
  const float* x = (const float*)d_in[0];
  const float* y = (const float*)d_in[1];
  float* out = (float*)d_out;
  float* F = (float*)d_ws;  // 32*512*512*4 = 33.5 MB, skewed ILP-4 layout

  dim3 g1(TN / 64, TN / 64, 32);
  // Swapped args -> values are bitwise D^T, stored skewed + log2e-scaled.
  pairdist_kernel<<<g1, 256, 0, stream>>>(y, x, F);
  sdtw_kernel<<<32, 64, 0, stream>>>(F, out);
}

// Round 9
// 256.872 us; speedup vs baseline: 1.1070x; 1.1070x over previous
//
#include <hip/hip_runtime.h>
#include <hip/hip_bf16.h>

#define BIGF 1e30f
#define TC 80   // channels
#define TN 512  // sequence length (N == M)
#define L2E 1.4426950408889634f   // log2(e)
#define LN2 0.6931471805599453f   // 1/log2(e)

typedef float f32x2 __attribute__((ext_vector_type(2)));
typedef float f32x4 __attribute__((ext_vector_type(4)));
typedef __attribute__((address_space(1))) const unsigned int gu32;
typedef __attribute__((address_space(3))) unsigned int lu32;

// ---------------------------------------------------------------------------
// Kernel 1: pairwise squared distances, SKEWED layout, log2e-scaled.
// UNCHANGED from round 8 (verified absmax 0.0).
// Storage: F[p][i], p = (jj + (i>>1)) & 511; pipeline v = i>>1 owns 2 rows.
// At sweep iteration s all pipelines read row p = s & 511 (uniform 2 KB).
// ---------------------------------------------------------------------------
__global__ __launch_bounds__(256) void pairdist_kernel(
    const float* __restrict__ x, const float* __restrict__ y,
    float* __restrict__ F) {
  const int b  = blockIdx.z;
  const int n0 = blockIdx.x * 64;   // jj tile (rows of D')
  const int m0 = blockIdx.y * 64;   // i tile (cols of D')

  __shared__ float xs[TC][64];
  __shared__ float ys[TC][64];
  __shared__ float xxs[64];
  __shared__ float yys[64];

  const float* xb = x + (size_t)b * TC * TN;
  const float* yb = y + (size_t)b * TC * TN;
  const int tid = threadIdx.x;

  for (int idx = tid; idx < TC * 64; idx += 256) {
    int c = idx >> 6, n = idx & 63;
    xs[c][n] = xb[c * TN + n0 + n];
    ys[c][n] = yb[c * TN + m0 + n];
  }
  __syncthreads();

  if (tid < 64) {
    float s = 0.f;
    for (int c = 0; c < TC; ++c) { float v = xs[c][tid]; s += v * v; }
    xxs[tid] = s;
  } else if (tid < 128) {
    int t2 = tid - 64;
    float s = 0.f;
    for (int c = 0; c < TC; ++c) { float v = ys[c][t2]; s += v * v; }
    yys[t2] = s;
  }
  __syncthreads();

  const int tm = tid & 15, tn = tid >> 4;
  float acc[4][4] = {};
  for (int c = 0; c < TC; ++c) {
    float4 xa = *(const float4*)&xs[c][tn * 4];
    float4 ya = *(const float4*)&ys[c][tm * 4];
    float xv[4] = {xa.x, xa.y, xa.z, xa.w};
    float yv[4] = {ya.x, ya.y, ya.z, ya.w};
#pragma unroll
    for (int a = 0; a < 4; ++a)
#pragma unroll
      for (int q = 0; q < 4; ++q) acc[a][q] += xv[a] * yv[q];
  }

  float* Fb = F + (size_t)b * TN * TN;
  const int i0 = m0 + tm * 4;
  const int v0 = i0 >> 1;
#pragma unroll
  for (int a = 0; a < 4; ++a) {
    int jj = n0 + tn * 4 + a;
    float xxv = xxs[tn * 4 + a];
    float4 o;
    o.x = (xxv + yys[tm * 4 + 0] - 2.f * acc[a][0]) * L2E;
    o.y = (xxv + yys[tm * 4 + 1] - 2.f * acc[a][1]) * L2E;
    o.z = (xxv + yys[tm * 4 + 2] - 2.f * acc[a][2]) * L2E;
    o.w = (xxv + yys[tm * 4 + 3] - 2.f * acc[a][3]) * L2E;
    int p0 = (jj + v0) & (TN - 1);
    int p1 = (jj + v0 + 1) & (TN - 1);
    *(float2*)&Fb[(size_t)p0 * TN + i0]     = make_float2(o.x, o.y);
    *(float2*)&Fb[(size_t)p1 * TN + i0 + 2] = make_float2(o.z, o.w);
  }
}

// ---------------------------------------------------------------------------
// Kernel 2: soft-DTW, 4-WAVE slab sweep (256 pipelines x 2 rows; wave w owns
// pipelines 64w..64w+63, lane g = pipeline 64w+g, DP rows 2v+1, 2v+2).
//
// Round-8 post-mortem: ONE wave is issue-floor-bound (~580 cy/iter no matter
// the chain shape). Split across 4 waves = 4 SIMDs: per-wave per-iter work
// drops 4x (2 cells/lane). 767 iterations (s = 0..766), col j = s - v + 1.
//
// Cross-wave handoff (consumer lane 0 up-row <- producer lane 63 bottom,
// 1-iter delay) via tagged LDS mailbox ring, depth 64: producer lane 63
// writes {value, tag=s} as ONE aligned ds_write_b64 (non-torn, DS in-order
// per wave); consumer polls tag >= s-1 (broadcast read; steady state 1 pass).
// NO __syncthreads in the loop (its vmcnt drain would kill the DMA ring);
// a RAW s_barrier once per 8-iter block bounds inter-wave skew to <=16
// iters << 64-slot ring -> a needed mailbox slot is never overwritten
// before its read (next overwrite is 64 iters > 2 blocks away). Mailboxes
// init'd to {BIG, -1}: pre-start consumers see exactly the BIG boundary.
//
// Per-wave D delivery: verified 8-slot LDS-ring machinery (2 width-4
// global_load_lds per slot = 16 outstanding, vmcnt(0) per block for loads
// staged one block earlier, batched 8x ds_read_b64 + lgkmcnt(0) in one asm).
// Cell math bit-identical to rounds 7/8 (absmax 0.0).
// ---------------------------------------------------------------------------
__global__ __launch_bounds__(256) __attribute__((amdgpu_waves_per_eu(1)))
void sdtw_kernel(const float* __restrict__ Ft, float* __restrict__ out) {
  const int b   = blockIdx.x;
  const int tid = threadIdx.x;
  const int g   = tid & 63;         // lane
  const int w   = tid >> 6;         // wave 0..3
  const float* Fb = Ft + (size_t)b * TN * TN;

  __shared__ float ring[4][8][128]; // per-wave 8 slots x 512 B
  __shared__ f32x2 hand[3][64];     // mailbox ring: {value, tag}

  // Init mailboxes to {BIG, -1} so pre-start polls succeed with BIG.
  if (tid < 192) {
    f32x2 iv; iv[0] = BIGF; iv[1] = __int_as_float(-1);
    hand[tid >> 6][tid & 63] = iv;
  }
  __syncthreads();                  // one-time; before any DMA is in flight

  float p0 = BIGF, p1 = BIGF;       // left values of my 2 rows
  float up_p = (tid == 0) ? 0.f : BIGF;   // R[2v][j-1]; R[0][0] = 0

  // Stage iteration u's data for this wave: row p = u & 511, cols 128w..+127.
  // Lane g sources col 128w+g (instr A) and 128w+64+g (instr B);
  // LDS dest = uniform base + 4*lane -> ring[w][slot][g] / [64+g].
  auto stage = [&](int slot, int u) {
    const float* gp = Fb + (size_t)(u & (TN - 1)) * TN + w * 128 + g;
    __builtin_amdgcn_global_load_lds((gu32*)gp,        (lu32*)&ring[w][slot][0],  4, 0, 0);
    __builtin_amdgcn_global_load_lds((gu32*)(gp + 64), (lu32*)&ring[w][slot][64], 4, 0, 0);
  };

  const unsigned rbase =
      (unsigned)(size_t)(__attribute__((address_space(3))) float*)&ring[w][0][0];
  const unsigned hbase =
      (unsigned)(size_t)(__attribute__((address_space(3))) f32x2*)&hand[0][0];

  // One DP cell, bit-identical to rounds 7/8 (exact min3/med3/max3 sort,
  // 2x exp2 + 1x log2, ss = (1 + e1) + e2).
  auto cell = [&](float d, float r0, float r1, float r2) -> float {
    float mn, md, mx;
    asm("v_min3_f32 %0, %3, %4, %5\n\t"
        "v_med3_f32 %1, %3, %4, %5\n\t"
        "v_max3_f32 %2, %3, %4, %5"
        : "=&v"(mn), "=&v"(md), "=&v"(mx)
        : "v"(r0), "v"(r1), "v"(r2));
    float e1 = __builtin_amdgcn_exp2f(mn - md);
    float e2 = __builtin_amdgcn_exp2f(mn - mx);
    float dm = d + mn;
    float ss = (1.0f + e1) + e2;
    return dm - __builtin_amdgcn_logf(ss);
  };

  auto body = [&](int s, f32x2 d) {
    // Up-row value for lane 0: wave w-1 lane 63's bottom from iter s-1.
    float val;
    if (w > 0) {
      unsigned ha = hbase + (unsigned)((w - 1) * 512 + ((s - 1) & 63) * 8);
      f32x2 hv;
      do {
        asm volatile("ds_read_b64 %0, %1\n\ts_waitcnt lgkmcnt(0)"
                     : "=v"(hv) : "v"(ha) : "memory");
      } while (__float_as_int(hv[1]) < s - 1);
      val = hv[0];
    } else {
      val = BIGF;                   // R[0][j] = BIG for j >= 1
    }
    // Within-wave handoff: lane g gets lane g-1's bottom (1-iter delay);
    // lane 0 takes the mailbox/BIG value.
    float upc = __int_as_float(__builtin_amdgcn_update_dpp(
        __float_as_int(val), __float_as_int(p1), 0x138, 0xf, 0xf, false));

    float c0 = cell(d[0], up_p, upc, p0);   // top row of my pipeline
    float c1 = cell(d[1], p0, c0, p1);      // bottom row

    if (w < 3 && g == 63) {                 // publish bottom for next wave
      f32x2 pk; pk[0] = c1; pk[1] = __int_as_float(s);
      unsigned wa = hbase + (unsigned)(w * 512 + (s & 63) * 8);
      asm volatile("ds_write_b64 %0, %1" :: "v"(wa), "v"(pk) : "memory");
    }
    p0 = c0; p1 = c1; up_p = upc;
  };

  // Preamble: stage slots 0..7 (iters 0..7) -> 16 outstanding DMA per wave.
  stage(0, 0); stage(1, 1); stage(2, 2); stage(3, 3);
  stage(4, 4); stage(5, 5); stage(6, 6); stage(7, 7);

  f32x2 d0, d1, d2, d3, d4, d5, d6, d7;

  // Main: 95 blocks x 8 bodies (iters 0..759).
  int s = 0;
  for (int blk = 0; blk < 95; ++blk, s += 8) {
    __builtin_amdgcn_s_barrier();   // raw: bounds wave skew, drains nothing
    asm volatile("s_waitcnt vmcnt(0)" ::: "memory");  // staged 1 block ago
    unsigned ad = rbase + (unsigned)(g * 8);          // my float2 per slot
    asm volatile(
        "ds_read_b64 %0, %8\n\t"
        "ds_read_b64 %1, %8 offset:512\n\t"
        "ds_read_b64 %2, %8 offset:1024\n\t"
        "ds_read_b64 %3, %8 offset:1536\n\t"
        "ds_read_b64 %4, %8 offset:2048\n\t"
        "ds_read_b64 %5, %8 offset:2560\n\t"
        "ds_read_b64 %6, %8 offset:3072\n\t"
        "ds_read_b64 %7, %8 offset:3584\n\t"
        "s_waitcnt lgkmcnt(0)"
        : "=&v"(d0), "=&v"(d1), "=&v"(d2), "=&v"(d3),
          "=&v"(d4), "=&v"(d5), "=&v"(d6), "=&v"(d7)
        : "v"(ad)
        : "memory");
    // Refill all 8 slots for the NEXT block (reads above already complete).
    stage(0, s + 8);  stage(1, s + 9);
    stage(2, s + 10); stage(3, s + 11);
    stage(4, s + 12); stage(5, s + 13);
    stage(6, s + 14); stage(7, s + 15);

    body(s + 0, d0); body(s + 1, d1); body(s + 2, d2); body(s + 3, d3);
    body(s + 4, d4); body(s + 5, d5); body(s + 6, d6); body(s + 7, d7);
  }

  // Tail: iters 760..766 (7 bodies, slots 0..6; no refills).
  __builtin_amdgcn_s_barrier();
  asm volatile("s_waitcnt vmcnt(0)" ::: "memory");
  {
    unsigned ad = rbase + (unsigned)(g * 8);
    asm volatile(
        "ds_read_b64 %0, %7\n\t"
        "ds_read_b64 %1, %7 offset:512\n\t"
        "ds_read_b64 %2, %7 offset:1024\n\t"
        "ds_read_b64 %3, %7 offset:1536\n\t"
        "ds_read_b64 %4, %7 offset:2048\n\t"
        "ds_read_b64 %5, %7 offset:2560\n\t"
        "ds_read_b64 %6, %7 offset:3072\n\t"
        "s_waitcnt lgkmcnt(0)"
        : "=&v"(d0), "=&v"(d1), "=&v"(d2), "=&v"(d3),
          "=&v"(d4), "=&v"(d5), "=&v"(d6)
        : "v"(ad)
        : "memory");
  }
  body(760, d0); body(761, d1); body(762, d2); body(763, d3);
  body(764, d4); body(765, d5); body(766, d6);

  // R[512][512] = pipeline 255 (wave 3, lane 63) bottom row at s = 766.
  if (tid == 255) out[b] = p1 * LN2;
}

extern "C" void kernel_launch(void* const* d_in, const int* in_sizes, int n_in,
                              void* d_out, int out_size, void* d_ws, size_t ws_size,
                              hipStream_t stream) {
  const float* x = (const float*)d_in[0];
  const float* y = (const float*)d_in[1];
  float* out = (float*)d_out;
  float* F = (float*)d_ws;  // 32*512*512*4 = 33.5 MB, skewed layout

  dim3 g1(TN / 64, TN / 64, 32);
  // Swapped args -> values are bitwise D^T, stored skewed + log2e-scaled.
  pairdist_kernel<<<g1, 256, 0, stream>>>(y, x, F);
  sdtw_kernel<<<32, 256, 0, stream>>>(F, out);
}

// Round 10
// 193.104 us; speedup vs baseline: 1.4725x; 1.3302x over previous
//
#include <hip/hip_runtime.h>
#include <hip/hip_bf16.h>

#define BIGF 1e30f
#define TC 80   // channels
#define TN 512  // sequence length (N == M)
#define L2E 1.4426950408889634f   // log2(e)
#define LN2 0.6931471805599453f   // 1/log2(e)

typedef float f32x2 __attribute__((ext_vector_type(2)));
typedef float f32x4 __attribute__((ext_vector_type(4)));
typedef __attribute__((address_space(1))) const unsigned int gu32;
typedef __attribute__((address_space(3))) unsigned int lu32;

// ---------------------------------------------------------------------------
// Kernel 1: pairwise squared distances, SKEWED layout, log2e-scaled.
// UNCHANGED from rounds 8/9 (verified absmax 0.0).
// Storage: F[p][i], p = (jj + (i>>1)) & 511; pipeline v = i>>1 owns 2 rows.
// ---------------------------------------------------------------------------
__global__ __launch_bounds__(256) void pairdist_kernel(
    const float* __restrict__ x, const float* __restrict__ y,
    float* __restrict__ F) {
  const int b  = blockIdx.z;
  const int n0 = blockIdx.x * 64;   // jj tile (rows of D')
  const int m0 = blockIdx.y * 64;   // i tile (cols of D')

  __shared__ float xs[TC][64];
  __shared__ float ys[TC][64];
  __shared__ float xxs[64];
  __shared__ float yys[64];

  const float* xb = x + (size_t)b * TC * TN;
  const float* yb = y + (size_t)b * TC * TN;
  const int tid = threadIdx.x;

  for (int idx = tid; idx < TC * 64; idx += 256) {
    int c = idx >> 6, n = idx & 63;
    xs[c][n] = xb[c * TN + n0 + n];
    ys[c][n] = yb[c * TN + m0 + n];
  }
  __syncthreads();

  if (tid < 64) {
    float s = 0.f;
    for (int c = 0; c < TC; ++c) { float v = xs[c][tid]; s += v * v; }
    xxs[tid] = s;
  } else if (tid < 128) {
    int t2 = tid - 64;
    float s = 0.f;
    for (int c = 0; c < TC; ++c) { float v = ys[c][t2]; s += v * v; }
    yys[t2] = s;
  }
  __syncthreads();

  const int tm = tid & 15, tn = tid >> 4;
  float acc[4][4] = {};
  for (int c = 0; c < TC; ++c) {
    float4 xa = *(const float4*)&xs[c][tn * 4];
    float4 ya = *(const float4*)&ys[c][tm * 4];
    float xv[4] = {xa.x, xa.y, xa.z, xa.w};
    float yv[4] = {ya.x, ya.y, ya.z, ya.w};
#pragma unroll
    for (int a = 0; a < 4; ++a)
#pragma unroll
      for (int q = 0; q < 4; ++q) acc[a][q] += xv[a] * yv[q];
  }

  float* Fb = F + (size_t)b * TN * TN;
  const int i0 = m0 + tm * 4;
  const int v0 = i0 >> 1;
#pragma unroll
  for (int a = 0; a < 4; ++a) {
    int jj = n0 + tn * 4 + a;
    float xxv = xxs[tn * 4 + a];
    float4 o;
    o.x = (xxv + yys[tm * 4 + 0] - 2.f * acc[a][0]) * L2E;
    o.y = (xxv + yys[tm * 4 + 1] - 2.f * acc[a][1]) * L2E;
    o.z = (xxv + yys[tm * 4 + 2] - 2.f * acc[a][2]) * L2E;
    o.w = (xxv + yys[tm * 4 + 3] - 2.f * acc[a][3]) * L2E;
    int p0 = (jj + v0) & (TN - 1);
    int p1 = (jj + v0 + 1) & (TN - 1);
    *(float2*)&Fb[(size_t)p0 * TN + i0]     = make_float2(o.x, o.y);
    *(float2*)&Fb[(size_t)p1 * TN + i0 + 2] = make_float2(o.z, o.w);
  }
}

// ---------------------------------------------------------------------------
// Kernel 2: soft-DTW, 4-wave slab sweep with BLOCK-BATCHED cross-wave
// handoff (no per-iteration polling — round-9's bottleneck).
//
// Schedule: wave w, lane g runs pipeline v = 64w+g (DP rows 2v+1, 2v+2) at
// column j = s - 71w - g + 1 (extra 7-col skew per wave boundary). The
// consumer (wave w lane 0) therefore needs producer (wave w-1 lane 63)
// bottoms with an 8-ITERATION delay = exactly the previous block's 8 values:
//   - producer lane 63 publishes 8 bottoms as 2x ds_write_b128 + lgkmcnt(0)
//     at block end (parity slot B&1),
//   - consumer reads them as 2x broadcast ds_read_b128 at block top, after
//     the per-block raw s_barrier (which orders publish before read).
// Parity double-buffer kills overwrite races; slots init'd to BIG so
// pre-start consumers see the exact boundary value. Zero per-body DS ops.
//
// F-row per wave at iter s: p = (s - 7w) & 511 (uniform 512 B per wave;
// junk reads pre-start are finite pairdist values, absorbed bitwise by the
// BIG self-sustain: 1e30 + small - log2(3) -> 1e30 exact in fp32).
//
// 788 iterations = 98 blocks x 8 + 4 tail. Per-wave D delivery machinery
// (8-slot LDS ring, 16 outstanding width-4 global_load_lds, vmcnt(0) per
// block for loads staged one block earlier, batched 8x ds_read_b64 +
// lgkmcnt(0)) is the round-9 verified structure. Cell math bit-identical
// to rounds 7-9 (absmax 0.0).
// ---------------------------------------------------------------------------
__global__ __launch_bounds__(256) __attribute__((amdgpu_waves_per_eu(1)))
void sdtw_kernel(const float* __restrict__ Ft, float* __restrict__ out) {
  const int b   = blockIdx.x;
  const int tid = threadIdx.x;
  const int g   = tid & 63;         // lane
  const int w   = tid >> 6;         // wave 0..3
  const float* Fb = Ft + (size_t)b * TN * TN;

  __shared__ float ring[4][8][128];       // per-wave 8 slots x 512 B
  __shared__ f32x4 hand[3][2][2];         // [boundary][parity][2x f32x4]

  // Init mailboxes to BIG (pre-start consumers read the boundary value).
  if (tid < 12) {
    f32x4 iv; iv[0] = BIGF; iv[1] = BIGF; iv[2] = BIGF; iv[3] = BIGF;
    ((f32x4*)hand)[tid] = iv;
  }
  __syncthreads();                  // one-time; before any DMA is in flight

  float p0 = BIGF, p1 = BIGF;       // left values of my 2 rows
  float up_p = (tid == 0) ? 0.f : BIGF;   // R[2v][j-1]; R[0][0] = 0

  // Stage iteration u for this wave: row (u-7w)&511, cols 128w..128w+127.
  auto stage = [&](int slot, int u) {
    const float* gp =
        Fb + (size_t)((u - 7 * w) & (TN - 1)) * TN + w * 128 + g;
    __builtin_amdgcn_global_load_lds((gu32*)gp,        (lu32*)&ring[w][slot][0],  4, 0, 0);
    __builtin_amdgcn_global_load_lds((gu32*)(gp + 64), (lu32*)&ring[w][slot][64], 4, 0, 0);
  };

  const unsigned rbase =
      (unsigned)(size_t)(__attribute__((address_space(3))) float*)&ring[w][0][0];
  const unsigned hbase =
      (unsigned)(size_t)(__attribute__((address_space(3))) f32x4*)&hand[0][0];

  // One DP cell, bit-identical to rounds 7-9.
  auto cell = [&](float d, float r0, float r1, float r2) -> float {
    float mn, md, mx;
    asm("v_min3_f32 %0, %3, %4, %5\n\t"
        "v_med3_f32 %1, %3, %4, %5\n\t"
        "v_max3_f32 %2, %3, %4, %5"
        : "=&v"(mn), "=&v"(md), "=&v"(mx)
        : "v"(r0), "v"(r1), "v"(r2));
    float e1 = __builtin_amdgcn_exp2f(mn - md);
    float e2 = __builtin_amdgcn_exp2f(mn - mx);
    float dm = d + mn;
    float ss = (1.0f + e1) + e2;
    return dm - __builtin_amdgcn_logf(ss);
  };

  // Body: pubk = producer bottom from iter s-8 (wave-uniform broadcast;
  // BIG for wave 0). Lane g's up value comes from lane g-1 (1-iter delay)
  // via DPP wave_shr:1; lane 0 takes pubk. Returns my bottom (for publish).
  auto body = [&](f32x2 d, float pubk) -> float {
    float upc = __int_as_float(__builtin_amdgcn_update_dpp(
        __float_as_int(pubk), __float_as_int(p1), 0x138, 0xf, 0xf, false));
    float c0 = cell(d[0], up_p, upc, p0);   // top row
    float c1 = cell(d[1], p0, c0, p1);      // bottom row
    p0 = c0; p1 = c1; up_p = upc;
    return c1;
  };

  // Preamble: stage slots 0..7 (iters 0..7) -> 16 outstanding DMA per wave.
  stage(0, 0); stage(1, 1); stage(2, 2); stage(3, 3);
  stage(4, 4); stage(5, 5); stage(6, 6); stage(7, 7);

  f32x2 d0, d1, d2, d3, d4, d5, d6, d7;

  // Main: 98 blocks x 8 bodies (iters 0..783).
  int s = 0;
  for (int B = 0; B < 98; ++B, s += 8) {
    __builtin_amdgcn_s_barrier();   // raw: orders publish(B-1) before read
    asm volatile("s_waitcnt vmcnt(0)" ::: "memory");  // staged 1 block ago

    unsigned ad = rbase + (unsigned)(g * 8);          // my float2 per slot
    asm volatile(
        "ds_read_b64 %0, %8\n\t"
        "ds_read_b64 %1, %8 offset:512\n\t"
        "ds_read_b64 %2, %8 offset:1024\n\t"
        "ds_read_b64 %3, %8 offset:1536\n\t"
        "ds_read_b64 %4, %8 offset:2048\n\t"
        "ds_read_b64 %5, %8 offset:2560\n\t"
        "ds_read_b64 %6, %8 offset:3072\n\t"
        "ds_read_b64 %7, %8 offset:3584\n\t"
        "s_waitcnt lgkmcnt(0)"
        : "=&v"(d0), "=&v"(d1), "=&v"(d2), "=&v"(d3),
          "=&v"(d4), "=&v"(d5), "=&v"(d6), "=&v"(d7)
        : "v"(ad)
        : "memory");

    // Previous block's 8 producer bottoms (parity (B-1)&1 == (B+1)&1).
    f32x4 pA, pB;
    if (w > 0) {
      unsigned ha = hbase + (unsigned)(((w - 1) * 2 + ((B + 1) & 1)) * 32);
      asm volatile("ds_read_b128 %0, %2\n\t"
                   "ds_read_b128 %1, %2 offset:16\n\t"
                   "s_waitcnt lgkmcnt(0)"
                   : "=&v"(pA), "=&v"(pB) : "v"(ha) : "memory");
    } else {
      pA[0] = pA[1] = pA[2] = pA[3] = BIGF;
      pB[0] = pB[1] = pB[2] = pB[3] = BIGF;
    }

    // Refill all 8 slots for the NEXT block (ds_reads above are complete).
    stage(0, s + 8);  stage(1, s + 9);
    stage(2, s + 10); stage(3, s + 11);
    stage(4, s + 12); stage(5, s + 13);
    stage(6, s + 14); stage(7, s + 15);

    f32x4 k0, k1;
    k0[0] = body(d0, pA[0]); k0[1] = body(d1, pA[1]);
    k0[2] = body(d2, pA[2]); k0[3] = body(d3, pA[3]);
    k1[0] = body(d4, pB[0]); k1[1] = body(d5, pB[1]);
    k1[2] = body(d6, pB[2]); k1[3] = body(d7, pB[3]);

    // Publish this block's 8 bottoms for the next wave (parity B&1).
    if (w < 3 && g == 63) {
      unsigned wa = hbase + (unsigned)((w * 2 + (B & 1)) * 32);
      asm volatile("ds_write_b128 %0, %1\n\t"
                   "ds_write_b128 %0, %2 offset:16\n\t"
                   "s_waitcnt lgkmcnt(0)"
                   :: "v"(wa), "v"(k0), "v"(k1) : "memory");
    }
  }

  // Tail: iters 784..787 (4 bodies, slots 0..3, staged during block 97).
  __builtin_amdgcn_s_barrier();
  asm volatile("s_waitcnt vmcnt(0)" ::: "memory");
  {
    unsigned ad = rbase + (unsigned)(g * 8);
    asm volatile(
        "ds_read_b64 %0, %4\n\t"
        "ds_read_b64 %1, %4 offset:512\n\t"
        "ds_read_b64 %2, %4 offset:1024\n\t"
        "ds_read_b64 %3, %4 offset:1536\n\t"
        "s_waitcnt lgkmcnt(0)"
        : "=&v"(d0), "=&v"(d1), "=&v"(d2), "=&v"(d3)
        : "v"(ad)
        : "memory");
  }
  f32x4 pA;
  if (w > 0) {
    // Producer block-97 values, parity 97&1 = 1; need positions 0..3.
    unsigned ha = hbase + (unsigned)(((w - 1) * 2 + 1) * 32);
    asm volatile("ds_read_b128 %0, %1\n\ts_waitcnt lgkmcnt(0)"
                 : "=&v"(pA) : "v"(ha) : "memory");
  } else {
    pA[0] = pA[1] = pA[2] = pA[3] = BIGF;
  }
  body(d0, pA[0]); body(d1, pA[1]); body(d2, pA[2]); body(d3, pA[3]);

  // R[512][512] = pipeline 255 (wave 3, lane 63) bottom row at s = 787.
  if (tid == 255) out[b] = p1 * LN2;
}

extern "C" void kernel_launch(void* const* d_in, const int* in_sizes, int n_in,
                              void* d_out, int out_size, void* d_ws, size_t ws_size,
                              hipStream_t stream) {
  const float* x = (const float*)d_in[0];
  const float* y = (const float*)d_in[1];
  float* out = (float*)d_out;
  float* F = (float*)d_ws;  // 32*512*512*4 = 33.5 MB, skewed layout

  dim3 g1(TN / 64, TN / 64, 32);
  // Swapped args -> values are bitwise D^T, stored skewed + log2e-scaled.
  pairdist_kernel<<<g1, 256, 0, stream>>>(y, x, F);
  sdtw_kernel<<<32, 256, 0, stream>>>(F, out);
}

// Round 11
// 188.897 us; speedup vs baseline: 1.5053x; 1.0223x over previous
//
#include <hip/hip_runtime.h>
#include <hip/hip_bf16.h>

#define BIGF 1e30f
#define TC 80   // channels
#define TN 512  // sequence length (N == M)
#define L2E 1.4426950408889634f   // log2(e)
#define LN2 0.6931471805599453f   // 1/log2(e)

typedef float f32x2 __attribute__((ext_vector_type(2)));
typedef float f32x4 __attribute__((ext_vector_type(4)));
typedef __attribute__((address_space(1))) const unsigned int gu32;
typedef __attribute__((address_space(3))) unsigned int lu32;

// ---------------------------------------------------------------------------
// Kernel 1: pairwise squared distances, SKEWED layout, log2e-scaled.
// ROUND-11 REWRITE: 128x128 tiles, 8x8 register blocking, C staged in two
// 40-channel phases (41 KB LDS -> 3 blocks/CU). Per c-step: 4 ds_read_b128
// feed 64 FMA (FMA-bound, vs 16 FMA per 2 reads before). Global reads drop
// 84 -> 41 MB. Per-output math is BITWISE IDENTICAL to the verified round-8
// kernel: acc accumulates c ascending 0..79 (phase order preserves it),
// norms ascending, epilogue (xx + yy - 2*acc)*L2E, same skew-store map
// F[(jj + (i>>1)) & 511][i].
// ---------------------------------------------------------------------------
__global__ __launch_bounds__(256) void pairdist_kernel(
    const float* __restrict__ x, const float* __restrict__ y,
    float* __restrict__ F) {
  const int b  = blockIdx.z;
  const int n0 = blockIdx.x * 128;  // jj tile (rows of D')
  const int m0 = blockIdx.y * 128;  // i tile (cols of D')

  __shared__ float xs[40][128];
  __shared__ float ys[40][128];
  __shared__ float xxs[128];
  __shared__ float yys[128];

  const float* xb = x + (size_t)b * TC * TN;
  const float* yb = y + (size_t)b * TC * TN;
  const int tid = threadIdx.x;
  const int tm = tid & 15, tn = tid >> 4;   // 16x16 thread grid, 8x8 each
  const int nc = tid & 127;                 // norm column
  const bool isX = tid < 128;

  float acc[8][8] = {};
  float nrm = 0.f;

  for (int half = 0; half < 2; ++half) {
    const int c0 = half * 40;
    // Stage 40x128 of each array: 1280 float4 per array, 5 per thread.
    for (int idx = tid; idx < 1280; idx += 256) {
      int c = idx >> 5, q = idx & 31;
      *(float4*)&xs[c][q * 4] =
          *(const float4*)&xb[(size_t)(c0 + c) * TN + n0 + q * 4];
      *(float4*)&ys[c][q * 4] =
          *(const float4*)&yb[(size_t)(c0 + c) * TN + m0 + q * 4];
    }
    __syncthreads();

    // Norm partial sums (register-carried across phases; c ascending).
    if (isX) {
      for (int c = 0; c < 40; ++c) { float v = xs[c][nc]; nrm += v * v; }
    } else {
      for (int c = 0; c < 40; ++c) { float v = ys[c][nc]; nrm += v * v; }
    }

    // 8x8 register-blocked inner product over this phase's 40 channels.
    for (int c = 0; c < 40; ++c) {
      float4 xa0 = *(const float4*)&xs[c][tn * 8];
      float4 xa1 = *(const float4*)&xs[c][tn * 8 + 4];
      float4 ya0 = *(const float4*)&ys[c][tm * 8];
      float4 ya1 = *(const float4*)&ys[c][tm * 8 + 4];
      float xv[8] = {xa0.x, xa0.y, xa0.z, xa0.w, xa1.x, xa1.y, xa1.z, xa1.w};
      float yv[8] = {ya0.x, ya0.y, ya0.z, ya0.w, ya1.x, ya1.y, ya1.z, ya1.w};
#pragma unroll
      for (int a2 = 0; a2 < 8; ++a2)
#pragma unroll
        for (int q2 = 0; q2 < 8; ++q2) acc[a2][q2] += xv[a2] * yv[q2];
    }
    __syncthreads();   // phase 0: guard restage; phase 1: guard norm write
  }

  if (isX) xxs[nc] = nrm; else yys[nc] = nrm;
  __syncthreads();

  // Epilogue: skewed float2 stores (identical mapping/expression to before).
  float* Fb = F + (size_t)b * TN * TN;
  const int i0 = m0 + tm * 8;
  const int v0 = i0 >> 1;
#pragma unroll
  for (int a = 0; a < 8; ++a) {
    int jj = n0 + tn * 8 + a;
    float xxv = xxs[tn * 8 + a];
#pragma unroll
    for (int k = 0; k < 4; ++k) {
      float2 o;
      o.x = (xxv + yys[tm * 8 + 2 * k]     - 2.f * acc[a][2 * k])     * L2E;
      o.y = (xxv + yys[tm * 8 + 2 * k + 1] - 2.f * acc[a][2 * k + 1]) * L2E;
      int p = (jj + v0 + k) & (TN - 1);
      *(float2*)&Fb[(size_t)p * TN + i0 + 2 * k] = o;
    }
  }
}

// ---------------------------------------------------------------------------
// Kernel 2: soft-DTW, 4-wave slab sweep with BLOCK-BATCHED cross-wave
// handoff. BYTE-IDENTICAL to the verified round-10 kernel (98.3 us,
// absmax 0.0). See round-10 comments for the full invariant ledger.
// ---------------------------------------------------------------------------
__global__ __launch_bounds__(256) __attribute__((amdgpu_waves_per_eu(1)))
void sdtw_kernel(const float* __restrict__ Ft, float* __restrict__ out) {
  const int b   = blockIdx.x;
  const int tid = threadIdx.x;
  const int g   = tid & 63;         // lane
  const int w   = tid >> 6;         // wave 0..3
  const float* Fb = Ft + (size_t)b * TN * TN;

  __shared__ float ring[4][8][128];       // per-wave 8 slots x 512 B
  __shared__ f32x4 hand[3][2][2];         // [boundary][parity][2x f32x4]

  // Init mailboxes to BIG (pre-start consumers read the boundary value).
  if (tid < 12) {
    f32x4 iv; iv[0] = BIGF; iv[1] = BIGF; iv[2] = BIGF; iv[3] = BIGF;
    ((f32x4*)hand)[tid] = iv;
  }
  __syncthreads();                  // one-time; before any DMA is in flight

  float p0 = BIGF, p1 = BIGF;       // left values of my 2 rows
  float up_p = (tid == 0) ? 0.f : BIGF;   // R[2v][j-1]; R[0][0] = 0

  // Stage iteration u for this wave: row (u-7w)&511, cols 128w..128w+127.
  auto stage = [&](int slot, int u) {
    const float* gp =
        Fb + (size_t)((u - 7 * w) & (TN - 1)) * TN + w * 128 + g;
    __builtin_amdgcn_global_load_lds((gu32*)gp,        (lu32*)&ring[w][slot][0],  4, 0, 0);
    __builtin_amdgcn_global_load_lds((gu32*)(gp + 64), (lu32*)&ring[w][slot][64], 4, 0, 0);
  };

  const unsigned rbase =
      (unsigned)(size_t)(__attribute__((address_space(3))) float*)&ring[w][0][0];
  const unsigned hbase =
      (unsigned)(size_t)(__attribute__((address_space(3))) f32x4*)&hand[0][0];

  // One DP cell, bit-identical to rounds 7-10.
  auto cell = [&](float d, float r0, float r1, float r2) -> float {
    float mn, md, mx;
    asm("v_min3_f32 %0, %3, %4, %5\n\t"
        "v_med3_f32 %1, %3, %4, %5\n\t"
        "v_max3_f32 %2, %3, %4, %5"
        : "=&v"(mn), "=&v"(md), "=&v"(mx)
        : "v"(r0), "v"(r1), "v"(r2));
    float e1 = __builtin_amdgcn_exp2f(mn - md);
    float e2 = __builtin_amdgcn_exp2f(mn - mx);
    float dm = d + mn;
    float ss = (1.0f + e1) + e2;
    return dm - __builtin_amdgcn_logf(ss);
  };

  // Body: pubk = producer bottom from iter s-8 (wave-uniform broadcast;
  // BIG for wave 0). Lane g's up value comes from lane g-1 (1-iter delay)
  // via DPP wave_shr:1; lane 0 takes pubk. Returns my bottom (for publish).
  auto body = [&](f32x2 d, float pubk) -> float {
    float upc = __int_as_float(__builtin_amdgcn_update_dpp(
        __float_as_int(pubk), __float_as_int(p1), 0x138, 0xf, 0xf, false));
    float c0 = cell(d[0], up_p, upc, p0);   // top row
    float c1 = cell(d[1], p0, c0, p1);      // bottom row
    p0 = c0; p1 = c1; up_p = upc;
    return c1;
  };

  // Preamble: stage slots 0..7 (iters 0..7) -> 16 outstanding DMA per wave.
  stage(0, 0); stage(1, 1); stage(2, 2); stage(3, 3);
  stage(4, 4); stage(5, 5); stage(6, 6); stage(7, 7);

  f32x2 d0, d1, d2, d3, d4, d5, d6, d7;

  // Main: 98 blocks x 8 bodies (iters 0..783).
  int s = 0;
  for (int B = 0; B < 98; ++B, s += 8) {
    __builtin_amdgcn_s_barrier();   // raw: orders publish(B-1) before read
    asm volatile("s_waitcnt vmcnt(0)" ::: "memory");  // staged 1 block ago

    unsigned ad = rbase + (unsigned)(g * 8);          // my float2 per slot
    asm volatile(
        "ds_read_b64 %0, %8\n\t"
        "ds_read_b64 %1, %8 offset:512\n\t"
        "ds_read_b64 %2, %8 offset:1024\n\t"
        "ds_read_b64 %3, %8 offset:1536\n\t"
        "ds_read_b64 %4, %8 offset:2048\n\t"
        "ds_read_b64 %5, %8 offset:2560\n\t"
        "ds_read_b64 %6, %8 offset:3072\n\t"
        "ds_read_b64 %7, %8 offset:3584\n\t"
        "s_waitcnt lgkmcnt(0)"
        : "=&v"(d0), "=&v"(d1), "=&v"(d2), "=&v"(d3),
          "=&v"(d4), "=&v"(d5), "=&v"(d6), "=&v"(d7)
        : "v"(ad)
        : "memory");

    // Previous block's 8 producer bottoms (parity (B-1)&1 == (B+1)&1).
    f32x4 pA, pB;
    if (w > 0) {
      unsigned ha = hbase + (unsigned)(((w - 1) * 2 + ((B + 1) & 1)) * 32);
      asm volatile("ds_read_b128 %0, %2\n\t"
                   "ds_read_b128 %1, %2 offset:16\n\t"
                   "s_waitcnt lgkmcnt(0)"
                   : "=&v"(pA), "=&v"(pB) : "v"(ha) : "memory");
    } else {
      pA[0] = pA[1] = pA[2] = pA[3] = BIGF;
      pB[0] = pB[1] = pB[2] = pB[3] = BIGF;
    }

    // Refill all 8 slots for the NEXT block (ds_reads above are complete).
    stage(0, s + 8);  stage(1, s + 9);
    stage(2, s + 10); stage(3, s + 11);
    stage(4, s + 12); stage(5, s + 13);
    stage(6, s + 14); stage(7, s + 15);

    f32x4 k0, k1;
    k0[0] = body(d0, pA[0]); k0[1] = body(d1, pA[1]);
    k0[2] = body(d2, pA[2]); k0[3] = body(d3, pA[3]);
    k1[0] = body(d4, pB[0]); k1[1] = body(d5, pB[1]);
    k1[2] = body(d6, pB[2]); k1[3] = body(d7, pB[3]);

    // Publish this block's 8 bottoms for the next wave (parity B&1).
    if (w < 3 && g == 63) {
      unsigned wa = hbase + (unsigned)((w * 2 + (B & 1)) * 32);
      asm volatile("ds_write_b128 %0, %1\n\t"
                   "ds_write_b128 %0, %2 offset:16\n\t"
                   "s_waitcnt lgkmcnt(0)"
                   :: "v"(wa), "v"(k0), "v"(k1) : "memory");
    }
  }

  // Tail: iters 784..787 (4 bodies, slots 0..3, staged during block 97).
  __builtin_amdgcn_s_barrier();
  asm volatile("s_waitcnt vmcnt(0)" ::: "memory");
  {
    unsigned ad = rbase + (unsigned)(g * 8);
    asm volatile(
        "ds_read_b64 %0, %4\n\t"
        "ds_read_b64 %1, %4 offset:512\n\t"
        "ds_read_b64 %2, %4 offset:1024\n\t"
        "ds_read_b64 %3, %4 offset:1536\n\t"
        "s_waitcnt lgkmcnt(0)"
        : "=&v"(d0), "=&v"(d1), "=&v"(d2), "=&v"(d3)
        : "v"(ad)
        : "memory");
  }
  f32x4 pA;
  if (w > 0) {
    // Producer block-97 values, parity 97&1 = 1; need positions 0..3.
    unsigned ha = hbase + (unsigned)(((w - 1) * 2 + 1) * 32);
    asm volatile("ds_read_b128 %0, %1\n\ts_waitcnt lgkmcnt(0)"
                 : "=&v"(pA) : "v"(ha) : "memory");
  } else {
    pA[0] = pA[1] = pA[2] = pA[3] = BIGF;
  }
  body(d0, pA[0]); body(d1, pA[1]); body(d2, pA[2]); body(d3, pA[3]);

  // R[512][512] = pipeline 255 (wave 3, lane 63) bottom row at s = 787.
  if (tid == 255) out[b] = p1 * LN2;
}

extern "C" void kernel_launch(void* const* d_in, const int* in_sizes, int n_in,
                              void* d_out, int out_size, void* d_ws, size_t ws_size,
                              hipStream_t stream) {
  const float* x = (const float*)d_in[0];
  const float* y = (const float*)d_in[1];
  float* out = (float*)d_out;
  float* F = (float*)d_ws;  // 32*512*512*4 = 33.5 MB, skewed layout

  dim3 g1(TN / 128, TN / 128, 32);
  // Swapped args -> values are bitwise D^T, stored skewed + log2e-scaled.
  pairdist_kernel<<<g1, 256, 0, stream>>>(y, x, F);
  sdtw_kernel<<<32, 256, 0, stream>>>(F, out);
}

// Round 12
// 177.231 us; speedup vs baseline: 1.6044x; 1.0658x over previous
//
#include <hip/hip_runtime.h>
#include <hip/hip_bf16.h>

#define BIGF 1e30f
#define TC 80   // channels
#define TN 512  // sequence length (N == M)
#define L2E 1.4426950408889634f   // log2(e)
#define LN2 0.6931471805599453f   // 1/log2(e)

typedef float f32x2 __attribute__((ext_vector_type(2)));
typedef float f32x4 __attribute__((ext_vector_type(4)));
typedef short s16x8 __attribute__((ext_vector_type(8)));
typedef __attribute__((address_space(1))) const unsigned int gu32;
typedef __attribute__((address_space(3))) unsigned int lu32;

// ---------------------------------------------------------------------------
// Kernel 1: pairwise squared distances via BF16 MFMA, skewed store, log2e.
//
// Round-12: four fp32-VALU pairdist variants all pinned at ~94 us -> switch
// the 671M-FMA inner product to matrix cores. Threshold is 1607 (bf16-grade);
// bf16-rounded xy gives per-cell D error ~0.1-0.9, path-sum O(10) << 1607.
// Norms stay fp32-exact; only the -2*xy term is bf16.
//
// Structure: 128x128 tile/block, 4 waves (2x2), each 64x64 = 4x4 MFMA tiles
// x 3 K-steps (K=80 zero-padded to 96). A/B staged bf16 in LDS
// [128 rows][128 k] (256B stride; XOR swizzle byte^=(row&7)<<4, 16B-aligned,
// <=2-way conflicts = free). Staging: per-thread k-octet gather (8 coalesced
// global loads across lanes) -> one b128 LDS write.
// Fragment layouts (learn_hip-verified): A/B: row/col = lane&15,
// k = (lane>>4)*8 + j; D: col = lane&15, row = (lane>>4)*4 + reg.
// (An A/B-role swap would yield D instead of D^T; the softmin recurrence is
// exactly transpose-symmetric, so the final corner would be identical.)
// Store map unchanged: F[(jj + (i>>1)) & 511][i] = (xx+yy-2*acc)*L2E.
// ---------------------------------------------------------------------------
__global__ __launch_bounds__(256) void pairdist_kernel(
    const float* __restrict__ x, const float* __restrict__ y,
    float* __restrict__ F) {
  const int b  = blockIdx.z;
  const int n0 = blockIdx.x * 128;  // jj tile (A / M dim)
  const int m0 = blockIdx.y * 128;  // i tile  (B / N dim)

  __shared__ __align__(16) short Ab[128 * 128];  // bf16, 256B row stride
  __shared__ __align__(16) short Bb[128 * 128];
  __shared__ float xxs[128], yys[128];

  const float* xb = x + (size_t)b * TC * TN;
  const float* yb = y + (size_t)b * TC * TN;
  const int tid = threadIdx.x;

  // Swizzled byte offset of bf16 element [row][k]; k-octet base stays
  // 16B-aligned (XOR touches bits 4-6 only; 256B stride keeps it in-row).
  auto sw = [](int row, int k) -> int {
    return (row * 256 + k * 2) ^ ((row & 7) << 4);
  };
  auto cvt = [](float f) -> unsigned short {   // RNE f32 -> bf16
    unsigned u = __float_as_uint(f);
    return (unsigned short)((u + 0x7FFFu + ((u >> 16) & 1u)) >> 16);
  };

  // Stage 12 k-octets (c=0..79 data, 80..95 exact zeros) x 128 rows x 2.
  for (int item = tid; item < 12 * 128 * 2; item += 256) {
    int arr = (item >= 12 * 128) ? 1 : 0;
    int it  = item - arr * 12 * 128;
    int oct = it >> 7, n = it & 127;
    const float* src = arr ? (yb + m0 + n) : (xb + n0 + n);
    s16x8 pk;
#pragma unroll
    for (int j = 0; j < 8; ++j) {
      int c = oct * 8 + j;
      float v = (c < TC) ? src[(size_t)c * TN] : 0.f;
      pk[j] = (short)cvt(v);
    }
    short* dst = arr ? Bb : Ab;
    *(s16x8*)((char*)dst + sw(n, oct * 8)) = pk;
  }

  // Norms fp32-exact from global (coalesced per c across the half-block).
  if (tid < 128) {
    float s = 0.f;
    for (int c = 0; c < TC; ++c) {
      float v = xb[(size_t)c * TN + n0 + tid];
      s += v * v;
    }
    xxs[tid] = s;
  } else {
    int n = tid - 128;
    float s = 0.f;
    for (int c = 0; c < TC; ++c) {
      float v = yb[(size_t)c * TN + m0 + n];
      s += v * v;
    }
    yys[n] = s;
  }
  __syncthreads();

  // MFMA main: wave (wm, wn) computes 64x64.
  const int l  = tid & 63;
  const int w  = tid >> 6;
  const int wm = (w >> 1) * 64, wn = (w & 1) * 64;
  const int fr = l & 15;          // A-row / B-col index
  const int fk = (l >> 4) * 8;    // k base within K-step

  f32x4 acc[4][4] = {};
#pragma unroll
  for (int ks = 0; ks < 3; ++ks) {
    const int k0 = ks * 32 + fk;
    s16x8 af[4], bfr[4];
#pragma unroll
    for (int ta = 0; ta < 4; ++ta)
      af[ta] = *(const s16x8*)((const char*)Ab + sw(wm + ta * 16 + fr, k0));
#pragma unroll
    for (int tq = 0; tq < 4; ++tq)
      bfr[tq] = *(const s16x8*)((const char*)Bb + sw(wn + tq * 16 + fr, k0));
#pragma unroll
    for (int ta = 0; ta < 4; ++ta)
#pragma unroll
      for (int tq = 0; tq < 4; ++tq)
        acc[ta][tq] = __builtin_amdgcn_mfma_f32_16x16x32_bf16(
            af[ta], bfr[tq], acc[ta][tq], 0, 0, 0);
  }

  // Epilogue: D-layout col=lane&15, row=(lane>>4)*4+reg; skewed scalar
  // stores, identical mapping/expression to the verified round-11 kernel.
  float* Fb = F + (size_t)b * TN * TN;
#pragma unroll
  for (int ta = 0; ta < 4; ++ta) {
    const int mb = wm + ta * 16 + (l >> 4) * 4;
#pragma unroll
    for (int r = 0; r < 4; ++r) {
      const int jj = n0 + mb + r;
      const float xxv = xxs[mb + r];
#pragma unroll
      for (int tq = 0; tq < 4; ++tq) {
        const int nn = wn + tq * 16 + fr;
        const int i  = m0 + nn;
        float val = (xxv + yys[nn] - 2.f * acc[ta][tq][r]) * L2E;
        int p = (jj + (i >> 1)) & (TN - 1);
        Fb[(size_t)p * TN + i] = val;
      }
    }
  }
}

// ---------------------------------------------------------------------------
// Kernel 2: soft-DTW, 4-wave slab sweep with BLOCK-BATCHED cross-wave
// handoff. BYTE-IDENTICAL to the verified round-10/11 kernel (94.2 us,
// absmax 0.0). See round-10 comments for the full invariant ledger.
// ---------------------------------------------------------------------------
__global__ __launch_bounds__(256) __attribute__((amdgpu_waves_per_eu(1)))
void sdtw_kernel(const float* __restrict__ Ft, float* __restrict__ out) {
  const int b   = blockIdx.x;
  const int tid = threadIdx.x;
  const int g   = tid & 63;         // lane
  const int w   = tid >> 6;         // wave 0..3
  const float* Fb = Ft + (size_t)b * TN * TN;

  __shared__ float ring[4][8][128];       // per-wave 8 slots x 512 B
  __shared__ f32x4 hand[3][2][2];         // [boundary][parity][2x f32x4]

  // Init mailboxes to BIG (pre-start consumers read the boundary value).
  if (tid < 12) {
    f32x4 iv; iv[0] = BIGF; iv[1] = BIGF; iv[2] = BIGF; iv[3] = BIGF;
    ((f32x4*)hand)[tid] = iv;
  }
  __syncthreads();                  // one-time; before any DMA is in flight

  float p0 = BIGF, p1 = BIGF;       // left values of my 2 rows
  float up_p = (tid == 0) ? 0.f : BIGF;   // R[2v][j-1]; R[0][0] = 0

  // Stage iteration u for this wave: row (u-7w)&511, cols 128w..128w+127.
  auto stage = [&](int slot, int u) {
    const float* gp =
        Fb + (size_t)((u - 7 * w) & (TN - 1)) * TN + w * 128 + g;
    __builtin_amdgcn_global_load_lds((gu32*)gp,        (lu32*)&ring[w][slot][0],  4, 0, 0);
    __builtin_amdgcn_global_load_lds((gu32*)(gp + 64), (lu32*)&ring[w][slot][64], 4, 0, 0);
  };

  const unsigned rbase =
      (unsigned)(size_t)(__attribute__((address_space(3))) float*)&ring[w][0][0];
  const unsigned hbase =
      (unsigned)(size_t)(__attribute__((address_space(3))) f32x4*)&hand[0][0];

  // One DP cell, bit-identical to rounds 7-11.
  auto cell = [&](float d, float r0, float r1, float r2) -> float {
    float mn, md, mx;
    asm("v_min3_f32 %0, %3, %4, %5\n\t"
        "v_med3_f32 %1, %3, %4, %5\n\t"
        "v_max3_f32 %2, %3, %4, %5"
        : "=&v"(mn), "=&v"(md), "=&v"(mx)
        : "v"(r0), "v"(r1), "v"(r2));
    float e1 = __builtin_amdgcn_exp2f(mn - md);
    float e2 = __builtin_amdgcn_exp2f(mn - mx);
    float dm = d + mn;
    float ss = (1.0f + e1) + e2;
    return dm - __builtin_amdgcn_logf(ss);
  };

  // Body: pubk = producer bottom from iter s-8 (wave-uniform broadcast;
  // BIG for wave 0). Lane g's up value comes from lane g-1 (1-iter delay)
  // via DPP wave_shr:1; lane 0 takes pubk. Returns my bottom (for publish).
  auto body = [&](f32x2 d, float pubk) -> float {
    float upc = __int_as_float(__builtin_amdgcn_update_dpp(
        __float_as_int(pubk), __float_as_int(p1), 0x138, 0xf, 0xf, false));
    float c0 = cell(d[0], up_p, upc, p0);   // top row
    float c1 = cell(d[1], p0, c0, p1);      // bottom row
    p0 = c0; p1 = c1; up_p = upc;
    return c1;
  };

  // Preamble: stage slots 0..7 (iters 0..7) -> 16 outstanding DMA per wave.
  stage(0, 0); stage(1, 1); stage(2, 2); stage(3, 3);
  stage(4, 4); stage(5, 5); stage(6, 6); stage(7, 7);

  f32x2 d0, d1, d2, d3, d4, d5, d6, d7;

  // Main: 98 blocks x 8 bodies (iters 0..783).
  int s = 0;
  for (int B = 0; B < 98; ++B, s += 8) {
    __builtin_amdgcn_s_barrier();   // raw: orders publish(B-1) before read
    asm volatile("s_waitcnt vmcnt(0)" ::: "memory");  // staged 1 block ago

    unsigned ad = rbase + (unsigned)(g * 8);          // my float2 per slot
    asm volatile(
        "ds_read_b64 %0, %8\n\t"
        "ds_read_b64 %1, %8 offset:512\n\t"
        "ds_read_b64 %2, %8 offset:1024\n\t"
        "ds_read_b64 %3, %8 offset:1536\n\t"
        "ds_read_b64 %4, %8 offset:2048\n\t"
        "ds_read_b64 %5, %8 offset:2560\n\t"
        "ds_read_b64 %6, %8 offset:3072\n\t"
        "ds_read_b64 %7, %8 offset:3584\n\t"
        "s_waitcnt lgkmcnt(0)"
        : "=&v"(d0), "=&v"(d1), "=&v"(d2), "=&v"(d3),
          "=&v"(d4), "=&v"(d5), "=&v"(d6), "=&v"(d7)
        : "v"(ad)
        : "memory");

    // Previous block's 8 producer bottoms (parity (B-1)&1 == (B+1)&1).
    f32x4 pA, pB;
    if (w > 0) {
      unsigned ha = hbase + (unsigned)(((w - 1) * 2 + ((B + 1) & 1)) * 32);
      asm volatile("ds_read_b128 %0, %2\n\t"
                   "ds_read_b128 %1, %2 offset:16\n\t"
                   "s_waitcnt lgkmcnt(0)"
                   : "=&v"(pA), "=&v"(pB) : "v"(ha) : "memory");
    } else {
      pA[0] = pA[1] = pA[2] = pA[3] = BIGF;
      pB[0] = pB[1] = pB[2] = pB[3] = BIGF;
    }

    // Refill all 8 slots for the NEXT block (ds_reads above are complete).
    stage(0, s + 8);  stage(1, s + 9);
    stage(2, s + 10); stage(3, s + 11);
    stage(4, s + 12); stage(5, s + 13);
    stage(6, s + 14); stage(7, s + 15);

    f32x4 k0, k1;
    k0[0] = body(d0, pA[0]); k0[1] = body(d1, pA[1]);
    k0[2] = body(d2, pA[2]); k0[3] = body(d3, pA[3]);
    k1[0] = body(d4, pB[0]); k1[1] = body(d5, pB[1]);
    k1[2] = body(d6, pB[2]); k1[3] = body(d7, pB[3]);

    // Publish this block's 8 bottoms for the next wave (parity B&1).
    if (w < 3 && g == 63) {
      unsigned wa = hbase + (unsigned)((w * 2 + (B & 1)) * 32);
      asm volatile("ds_write_b128 %0, %1\n\t"
                   "ds_write_b128 %0, %2 offset:16\n\t"
                   "s_waitcnt lgkmcnt(0)"
                   :: "v"(wa), "v"(k0), "v"(k1) : "memory");
    }
  }

  // Tail: iters 784..787 (4 bodies, slots 0..3, staged during block 97).
  __builtin_amdgcn_s_barrier();
  asm volatile("s_waitcnt vmcnt(0)" ::: "memory");
  {
    unsigned ad = rbase + (unsigned)(g * 8);
    asm volatile(
        "ds_read_b64 %0, %4\n\t"
        "ds_read_b64 %1, %4 offset:512\n\t"
        "ds_read_b64 %2, %4 offset:1024\n\t"
        "ds_read_b64 %3, %4 offset:1536\n\t"
        "s_waitcnt lgkmcnt(0)"
        : "=&v"(d0), "=&v"(d1), "=&v"(d2), "=&v"(d3)
        : "v"(ad)
        : "memory");
  }
  f32x4 pA;
  if (w > 0) {
    // Producer block-97 values, parity 97&1 = 1; need positions 0..3.
    unsigned ha = hbase + (unsigned)(((w - 1) * 2 + 1) * 32);
    asm volatile("ds_read_b128 %0, %1\n\ts_waitcnt lgkmcnt(0)"
                 : "=&v"(pA) : "v"(ha) : "memory");
  } else {
    pA[0] = pA[1] = pA[2] = pA[3] = BIGF;
  }
  body(d0, pA[0]); body(d1, pA[1]); body(d2, pA[2]); body(d3, pA[3]);

  // R[512][512] = pipeline 255 (wave 3, lane 63) bottom row at s = 787.
  if (tid == 255) out[b] = p1 * LN2;
}

extern "C" void kernel_launch(void* const* d_in, const int* in_sizes, int n_in,
                              void* d_out, int out_size, void* d_ws, size_t ws_size,
                              hipStream_t stream) {
  const float* x = (const float*)d_in[0];
  const float* y = (const float*)d_in[1];
  float* out = (float*)d_out;
  float* F = (float*)d_ws;  // 32*512*512*4 = 33.5 MB, skewed layout

  dim3 g1(TN / 128, TN / 128, 32);
  // Swapped args -> values are D^T (up to bf16 rounding), skewed + scaled.
  pairdist_kernel<<<g1, 256, 0, stream>>>(y, x, F);
  sdtw_kernel<<<32, 256, 0, stream>>>(F, out);
}